// Round 1
// baseline (1714.296 us; speedup 1.0000x reference)
//
#include <hip/hip_runtime.h>

#define B_   8
#define H_   16
#define S_   1024
#define D_   64
#define BH_  128
#define QT   32

typedef __attribute__((ext_vector_type(8))) short  short8;
typedef __attribute__((ext_vector_type(4))) float  floatx4;

__device__ __forceinline__ unsigned short f2bf(float x) {
  unsigned u = __float_as_uint(x);
  u += 0x7FFFu + ((u >> 16) & 1u);     // round-to-nearest-even
  return (unsigned short)(u >> 16);
}
__device__ __forceinline__ float bf2f(unsigned short h) {
  return __uint_as_float(((unsigned)h) << 16);
}

// One block: 32 q-rows x full S for one (b,h).
// Wave layout: stripe = wave&1 -> m-rows [stripe*16, stripe*16+16)
//              npair  = wave>>1 -> n-tiles {2*npair, 2*npair+1} of each 64-col chunk
__global__ __launch_bounds__(256, 2)
void attn_fused(const float* __restrict__ q,
                const float* __restrict__ k,
                const float* __restrict__ v,
                const float* __restrict__ prev,
                const float* __restrict__ mask,
                const float* __restrict__ scale_p,
                float* __restrict__ outO,
                float* __restrict__ outW,
                float* __restrict__ outS) {
  __shared__ unsigned short ebuf[QT][S_ + 8];   // exp(scores) as bf16, 66,048 B
  __shared__ unsigned short stage[64][72];      // K: [s'][d] / V: [d][s'], 9,216 B
  __shared__ float rs[QT];                      // row sums of exp

  const int tid    = threadIdx.x;
  const int lane   = tid & 63;
  const int wave   = tid >> 6;
  const int l16    = lane & 15;
  const int quad   = lane >> 4;
  const int stripe = wave & 1;
  const int npair  = wave >> 1;

  const int bh = blockIdx.x & (BH_ - 1);
  const int qt = blockIdx.x >> 7;
  const int q0 = qt * QT;

  const float* qp = q    + ((size_t)bh * S_ + q0) * D_;
  const float* kp = k    + (size_t)bh * D_ * S_;
  const float* vp = v    + (size_t)bh * S_ * D_;
  const float* pp = prev + ((size_t)bh * S_ + q0) * S_;
  const float* mp = mask + (size_t)q0 * S_;
  const float  sc = scale_p[0];

  if (tid < QT) rs[tid] = 0.0f;

  // ---- load Q A-fragments (reused across all 16 chunks) ----
  // A[m = l16][k = quad*8 + j], m relative to stripe*16, k = d
  short8 aq[2];
  {
    const float* qrow = qp + (size_t)(stripe * 16 + l16) * D_ + quad * 8;
#pragma unroll
    for (int kc = 0; kc < 2; ++kc) {
      floatx4 f0 = *(const floatx4*)(qrow + kc * 32);
      floatx4 f1 = *(const floatx4*)(qrow + kc * 32 + 4);
      short8 a;
      a[0] = (short)f2bf(f0[0]); a[1] = (short)f2bf(f0[1]);
      a[2] = (short)f2bf(f0[2]); a[3] = (short)f2bf(f0[3]);
      a[4] = (short)f2bf(f1[0]); a[5] = (short)f2bf(f1[1]);
      a[6] = (short)f2bf(f1[2]); a[7] = (short)f2bf(f1[3]);
      aq[kc] = a;
    }
  }

  // ---- phase 1: scores = qk*mask*scale + prev; write scores; e=exp -> LDS ----
  float psum[4] = {0.f, 0.f, 0.f, 0.f};
  for (int nc = 0; nc < 16; ++nc) {
    const int s0 = nc * 64;
    __syncthreads();   // protect stage[] from prior-iteration readers
    {
      // stage K[d][s0+s'] -> stage[s'][d] (bf16), coalesced global reads
      const int drow = tid >> 4;
      const int s4   = (tid & 15) * 4;
#pragma unroll
      for (int p = 0; p < 4; ++p) {
        const int d = drow + p * 16;
        floatx4 f = *(const floatx4*)(kp + (size_t)d * S_ + s0 + s4);
        stage[s4 + 0][d] = f2bf(f[0]);
        stage[s4 + 1][d] = f2bf(f[1]);
        stage[s4 + 2][d] = f2bf(f[2]);
        stage[s4 + 3][d] = f2bf(f[3]);
      }
    }
    __syncthreads();

#pragma unroll
    for (int t = 0; t < 2; ++t) {
      const int nt = npair * 2 + t;
      const int n  = nt * 16 + l16;
      // B[n][k = quad*8+j] : k = d, contiguous in stage row
      short8 b0 = *(const short8*)&stage[n][quad * 8];
      short8 b1 = *(const short8*)&stage[n][32 + quad * 8];
      floatx4 c = {0.f, 0.f, 0.f, 0.f};
      c = __builtin_amdgcn_mfma_f32_16x16x32_bf16(aq[0], b0, c, 0, 0, 0);
      c = __builtin_amdgcn_mfma_f32_16x16x32_bf16(aq[1], b1, c, 0, 0, 0);

      // C/D layout: col = l16, row = quad*4 + r  (relative to stripe*16)
      const int col  = s0 + nt * 16 + l16;
      const int rowb = stripe * 16 + quad * 4;
#pragma unroll
      for (int r = 0; r < 4; ++r) {
        const int row = rowb + r;
        float mv  = mp[(size_t)row * S_ + col];
        float pv  = pp[(size_t)row * S_ + col];
        float scv = c[r] * mv * sc + pv;
        outS[((size_t)bh * S_ + q0 + row) * S_ + col] = scv;
        float e = __expf(scv);
        psum[r] += e;
        ebuf[row][col] = f2bf(e);
      }
    }
  }

  // ---- rowsum reduction: 16 lanes (l16) -> lane0 of each quad -> LDS atomic ----
#pragma unroll
  for (int m = 1; m <= 8; m <<= 1) {
#pragma unroll
    for (int r = 0; r < 4; ++r) psum[r] += __shfl_xor(psum[r], m, 64);
  }
  if (l16 == 0) {
    const int rowb = stripe * 16 + quad * 4;
#pragma unroll
    for (int r = 0; r < 4; ++r) atomicAdd(&rs[rowb + r], psum[r]);
  }

  // ---- phase 2: O = (e @ V) / rowsum ----
  floatx4 acc[2];
  acc[0] = (floatx4){0.f, 0.f, 0.f, 0.f};
  acc[1] = (floatx4){0.f, 0.f, 0.f, 0.f};
  for (int scn = 0; scn < 16; ++scn) {
    const int s0 = scn * 64;
    __syncthreads();   // also guarantees ebuf + rs complete on first iteration
    {
      // stage V[s0+s'][d] -> stage[d][s'] (bf16)
      const int srow = tid >> 4;
      const int d4   = (tid & 15) * 4;
#pragma unroll
      for (int p = 0; p < 4; ++p) {
        const int sv = srow + p * 16;
        floatx4 f = *(const floatx4*)(vp + (size_t)(s0 + sv) * D_ + d4);
        stage[d4 + 0][sv] = f2bf(f[0]);
        stage[d4 + 1][sv] = f2bf(f[1]);
        stage[d4 + 2][sv] = f2bf(f[2]);
        stage[d4 + 3][sv] = f2bf(f[3]);
      }
    }
    __syncthreads();

#pragma unroll
    for (int t = 0; t < 2; ++t) {
      const int nt = npair * 2 + t;    // d-tile
#pragma unroll
      for (int kk = 0; kk < 2; ++kk) {
        // A = e: m = l16 (row stripe*16+l16), k = s contiguous in ebuf row
        short8 ae = *(const short8*)&ebuf[stripe * 16 + l16][s0 + kk * 32 + quad * 8];
        // B = v: n = d = l16, k = s contiguous in stage row
        short8 bv = *(const short8*)&stage[nt * 16 + l16][kk * 32 + quad * 8];
        acc[t] = __builtin_amdgcn_mfma_f32_16x16x32_bf16(ae, bv, acc[t], 0, 0, 0);
      }
    }
  }

  // ---- O epilogue (rs complete: atomics preceded PV barriers) ----
  {
    const int rowb = stripe * 16 + quad * 4;
#pragma unroll
    for (int t = 0; t < 2; ++t) {
      const int dcol = (npair * 2 + t) * 16 + l16;
#pragma unroll
      for (int r = 0; r < 4; ++r) {
        const int row = rowb + r;
        outO[((size_t)bh * S_ + q0 + row) * D_ + dcol] = acc[t][r] / rs[row];
      }
    }
  }

  // ---- weights = e / rowsum, fully coalesced float4 sweep ----
  {
    float* wb = outW + ((size_t)bh * S_ + q0) * S_;
    const int c4 = tid * 4;   // 256 threads x 4 floats = one 1024-col row
    for (int row = 0; row < QT; ++row) {
      const float inv = 1.0f / rs[row];
      unsigned long long packed = *(const unsigned long long*)&ebuf[row][c4];
      floatx4 w;
      w[0] = bf2f((unsigned short)(packed      )) * inv;
      w[1] = bf2f((unsigned short)(packed >> 16)) * inv;
      w[2] = bf2f((unsigned short)(packed >> 32)) * inv;
      w[3] = bf2f((unsigned short)(packed >> 48)) * inv;
      *(floatx4*)(wb + (size_t)row * S_ + c4) = w;
    }
  }
}

extern "C" void kernel_launch(void* const* d_in, const int* in_sizes, int n_in,
                              void* d_out, int out_size, void* d_ws, size_t ws_size,
                              hipStream_t stream) {
  const float* q     = (const float*)d_in[0];
  const float* k     = (const float*)d_in[1];
  const float* v     = (const float*)d_in[2];
  const float* prev  = (const float*)d_in[3];
  const float* mask  = (const float*)d_in[4];
  const float* scale = (const float*)d_in[5];

  float* out  = (float*)d_out;
  float* outO = out;                                   // B*H*S*D  = 8,388,608
  float* outW = out + (size_t)B_ * H_ * S_ * D_;       // B*H*S*S  = 134,217,728
  float* outS = outW + (size_t)B_ * H_ * S_ * S_;

  dim3 grid(BH_ * (S_ / QT));   // 128 * 32 = 4096 blocks, bh-major for L2 reuse
  attn_fused<<<grid, 256, 0, stream>>>(q, k, v, prev, mask, scale, outO, outW, outS);
}